// Round 11
// baseline (237.770 us; speedup 1.0000x reference)
//
#include <hip/hip_runtime.h>
#include <hip/hip_bf16.h>
#include <math.h>

namespace {

constexpr int B = 2, C = 64, H = 80, W = 80, N = H * W;  // N = 6400
constexpr int NQ = 1600;   // 40*40
constexpr float EPS = 1e-5f;
constexpr int SAP = 8;           // pam flash m-chunks
constexpr int MCH = N / SAP;     // 800 m per chunk
constexpr int NMT_G = N / 32;    // 200 global m-tiles of 32
constexpr int NT3 = 400;         // conv3x3 pixel tiles (16 px each)
constexpr int NTC = 200;         // combine pixel tiles (32 px each)
constexpr float INV_BN = 1.0f / (float)(B * N);

typedef __attribute__((ext_vector_type(8))) short bf16x8;
typedef __attribute__((ext_vector_type(4))) float f32x4;

union U4H8 { uint4 u; bf16x8 h; };
union H8U { unsigned short s[8]; bf16x8 h; };
union WBU { __hip_bfloat162 h2[4]; bf16x8 h; };

__device__ __forceinline__ unsigned short f2bf(float x) {
  unsigned u = __builtin_bit_cast(unsigned, x);
  u += 0x7fffu + ((u >> 16) & 1u);   // RNE (no NaN inputs here)
  return (unsigned short)(u >> 16);
}
__device__ __forceinline__ float bf2f(unsigned short s) {
  return __builtin_bit_cast(float, (unsigned)s << 16);
}
__device__ __forceinline__ unsigned pack2(float x, float y) {
  return (unsigned)f2bf(x) | ((unsigned)f2bf(y) << 16);
}

// ---------------- merged: weight transforms (y<4) + x NCHW->NHWC bf16 (y==4) ------------
__global__ void xform_k(const float* __restrict__ x,
                        const float* __restrict__ Wc, const float* __restrict__ Wd,
                        const float* __restrict__ cqw, const float* __restrict__ ckw,
                        unsigned short* __restrict__ xt,
                        unsigned short* __restrict__ w9c, unsigned short* __restrict__ w9d,
                        unsigned short* __restrict__ w4q, unsigned short* __restrict__ w4k) {
  const int z = blockIdx.y;
  if (z < 4) {
    const int taps = (z < 2) ? 9 : 4;
    const float* src = (z == 0) ? Wc : (z == 1) ? Wd : (z == 2) ? cqw : ckw;
    unsigned short* dst = (z == 0) ? w9c : (z == 1) ? w9d : (z == 2) ? w4q : w4k;
    const int n = C * C * taps;
    const int i = blockIdx.x * 256 + threadIdx.x;
    if (i >= n) return;
    const int co = i / (C * taps), rem = i - co * (C * taps);
    const int ci = rem / taps, kk = rem - ci * taps;
    dst[(size_t)kk * (C * C) + co * C + ci] = f2bf(src[i]);
  } else {
    if (blockIdx.x >= B * N / 256) return;
    const int idx = blockIdx.x * 256 + threadIdx.x;  // b*N+p
    const int b = idx / N, p = idx - b * N;
    const float* ip = x + (size_t)b * C * N + p;
#pragma unroll
    for (int j = 0; j < 8; ++j) {
      H8U v;
#pragma unroll
      for (int i = 0; i < 8; ++i) v.s[i] = f2bf(ip[(size_t)(j * 8 + i) * N]);
      *(uint4*)&xt[(size_t)idx * C + j * 8] = *(uint4*)&v;
    }
  }
}

// ---------------- conv 3x3 pad 1 via implicit-GEMM MFMA, co split 4 ways ----------------
__global__ __launch_bounds__(256) void conv3x3_mfma_k(
    const unsigned short* __restrict__ in_t, const unsigned short* __restrict__ wt,
    float* __restrict__ out, float* __restrict__ part) {
  const int b = blockIdx.y, tile = blockIdx.x;  // 400 tiles of 16 pixels (within-row)
  const int wv = threadIdx.x >> 6;              // co-group
  const int lane = threadIdx.x & 63, ln15 = lane & 15, quad = lane >> 4;
  const int h = tile / 5, wbase = (tile - h * 5) * 16;
  const int w0 = wbase + ln15;
  const unsigned short* itb = in_t + (size_t)b * N * C;

  f32x4 acc = (f32x4){0.f, 0.f, 0.f, 0.f};

#pragma unroll
  for (int dh = -1; dh <= 1; ++dh) {
    const int hh = h + dh;
    if ((unsigned)hh >= (unsigned)H) continue;  // wave-uniform
#pragma unroll
    for (int dw = -1; dw <= 1; ++dw) {
      const bool valid = (unsigned)(w0 + dw) < (unsigned)W;
      const int pp = hh * W + (valid ? w0 + dw : w0);
      const uint4* bp = (const uint4*)(itb + (size_t)pp * C);
      U4H8 b0, b1;
      b0.u = bp[quad];
      b1.u = bp[4 + quad];
      if (!valid) { b0.u = make_uint4(0, 0, 0, 0); b1.u = make_uint4(0, 0, 0, 0); }
      const int kk = (dh + 1) * 3 + (dw + 1);
      const uint4* wp = (const uint4*)(wt + (size_t)kk * (C * C));
      U4H8 a0, a1;
      a0.u = wp[(wv * 16 + ln15) * 8 + quad];
      a1.u = wp[(wv * 16 + ln15) * 8 + 4 + quad];
      acc = __builtin_amdgcn_mfma_f32_16x16x32_bf16(a0.h, b0.h, acc, 0, 0, 0);
      acc = __builtin_amdgcn_mfma_f32_16x16x32_bf16(a1.h, b1.h, acc, 0, 0, 0);
    }
  }
  const int p = h * W + w0;
  float* ob = out + (size_t)b * C * N + p;
  const int cobase = wv * 16 + quad * 4;
  ob[(size_t)(cobase + 0) * N] = acc.x;
  ob[(size_t)(cobase + 1) * N] = acc.y;
  ob[(size_t)(cobase + 2) * N] = acc.z;
  ob[(size_t)(cobase + 3) * N] = acc.w;
  // per-channel partial stats over the 16 pixels; plain stores (no contention)
  const int bid = b * NT3 + tile;
  float v[4] = {acc.x, acc.y, acc.z, acc.w};
#pragma unroll
  for (int r = 0; r < 4; ++r) {
    float s = v[r], q = v[r] * v[r];
#pragma unroll
    for (int o = 1; o < 16; o <<= 1) {
      s += __shfl_xor(s, o);
      q += __shfl_xor(q, o);
    }
    if (ln15 == 0) {
      const int co = cobase + r;
      part[(size_t)co * (B * NT3) + bid] = s;
      part[(size_t)(64 + co) * (B * NT3) + bid] = q;
    }
  }
}

// ---------------- in-block stats reduce: part[128][n] -> sc_s/sh_s in LDS ----------------
// 2 threads per row, contiguous float4 streams, shfl-pair combine. No atomics.
__device__ __forceinline__ void reduce_stats(const float* __restrict__ part, int n,
                                             const float* __restrict__ g,
                                             const float* __restrict__ bt,
                                             float* sc_s, float* sh_s, float* raw) {
  const int row = threadIdx.x >> 1;  // 0..127
  const int half = threadIdx.x & 1;
  const int hn = n >> 1;
  const float* pr = part + (size_t)row * n + half * hn;
  float s = 0.f;
  for (int i = 0; i < hn; i += 4) {
    const float4 v = *(const float4*)&pr[i];
    s += (v.x + v.y) + (v.z + v.w);
  }
  s += __shfl_xor(s, 1);
  if (half == 0) raw[row] = s;
  __syncthreads();
  if (threadIdx.x < C) {
    const int c = threadIdx.x;
    const float m = raw[c] * INV_BN;
    const float var = raw[64 + c] * INV_BN - m * m;
    const float sc = rsqrtf(var + EPS) * g[c];
    sc_s[c] = sc;
    sh_s[c] = bt[c] - m * sc;
  }
  __syncthreads();
}

// ---------------- BN1: fused reduce + apply + relu -> feat1 (fp32 NCHW) + feat1h --------
__global__ __launch_bounds__(256) void bn1_apply_k(
    const float* __restrict__ y, const float* __restrict__ part,
    const float* __restrict__ g, const float* __restrict__ bt,
    float* __restrict__ feat1, unsigned short* __restrict__ feat1h) {
  __shared__ float sc_s[C], sh_s[C], raw[128];
  reduce_stats(part, B * NT3, g, bt, sc_s, sh_s, raw);
  const int idx = blockIdx.x * 256 + threadIdx.x;  // b*N+p
  const int b = idx / N, p = idx - b * N;
  const float* ip = y + (size_t)b * C * N + p;
  float* fp = feat1 + (size_t)b * C * N + p;
#pragma unroll
  for (int j = 0; j < 8; ++j) {
    H8U v;
#pragma unroll
    for (int i = 0; i < 8; ++i) {
      const int c = j * 8 + i;
      const float val = fmaxf(fmaf(ip[(size_t)c * N], sc_s[c], sh_s[c]), 0.f);
      fp[(size_t)c * N] = val;
      v.s[i] = f2bf(val);
    }
    *(uint4*)&feat1h[(size_t)idx * C + j * 8] = *(uint4*)&v;
  }
}

// ---------------- conv 2x2 stride 2 via MFMA, q & k in one wave, transposed out ----------
__global__ __launch_bounds__(64) void conv2x2_mfma_k(
    const unsigned short* __restrict__ feat1h,
    const unsigned short* __restrict__ w4q, const float* __restrict__ cqb,
    const unsigned short* __restrict__ w4k, const float* __restrict__ ckb,
    float* __restrict__ qT, float* __restrict__ kT) {
  const int b = blockIdx.y, tile = blockIdx.x;  // 100 tiles of 16 output px
  const int lane = threadIdx.x, ln15 = lane & 15, quad = lane >> 4;
  const int p = tile * 16 + ln15;               // 0..1599
  const int oh = p / 40, ow = p - oh * 40;
  const int pin = (oh * 2) * W + ow * 2;
  const unsigned short* itb = feat1h + (size_t)b * N * C;

  f32x4 aq[4], ak[4];
#pragma unroll
  for (int i = 0; i < 4; ++i) { aq[i] = (f32x4){0.f,0.f,0.f,0.f}; ak[i] = (f32x4){0.f,0.f,0.f,0.f}; }

#pragma unroll
  for (int dt = 0; dt < 4; ++dt) {
    const int dh = dt >> 1, dw = dt & 1;
    const uint4* bp = (const uint4*)(itb + (size_t)(pin + dh * W + dw) * C);
    U4H8 b0, b1;
    b0.u = bp[quad];
    b1.u = bp[4 + quad];
    const uint4* wq = (const uint4*)(w4q + (size_t)dt * (C * C));
    const uint4* wk = (const uint4*)(w4k + (size_t)dt * (C * C));
#pragma unroll
    for (int t4 = 0; t4 < 4; ++t4) {
      U4H8 a0, a1;
      a0.u = wq[(t4 * 16 + ln15) * 8 + quad];
      a1.u = wq[(t4 * 16 + ln15) * 8 + 4 + quad];
      aq[t4] = __builtin_amdgcn_mfma_f32_16x16x32_bf16(a0.h, b0.h, aq[t4], 0, 0, 0);
      aq[t4] = __builtin_amdgcn_mfma_f32_16x16x32_bf16(a1.h, b1.h, aq[t4], 0, 0, 0);
      a0.u = wk[(t4 * 16 + ln15) * 8 + quad];
      a1.u = wk[(t4 * 16 + ln15) * 8 + 4 + quad];
      ak[t4] = __builtin_amdgcn_mfma_f32_16x16x32_bf16(a0.h, b0.h, ak[t4], 0, 0, 0);
      ak[t4] = __builtin_amdgcn_mfma_f32_16x16x32_bf16(a1.h, b1.h, ak[t4], 0, 0, 0);
    }
  }
  float* qrow = qT + ((size_t)b * NQ + p) * C;
  float* krow = kT + ((size_t)b * NQ + p) * C;
#pragma unroll
  for (int t4 = 0; t4 < 4; ++t4) {
    const int co = t4 * 16 + quad * 4;
    const float4 bq = *(const float4*)&cqb[co];
    const float4 bk = *(const float4*)&ckb[co];
    *(float4*)&qrow[co] = make_float4(aq[t4].x + bq.x, aq[t4].y + bq.y,
                                      aq[t4].z + bq.z, aq[t4].w + bq.w);
    *(float4*)&krow[co] = make_float4(ak[t4].x + bk.x, ak[t4].y + bk.y,
                                      ak[t4].z + bk.z, ak[t4].w + bk.w);
  }
}

// ---------------- fused 1x1 projections, 8 co per block ----------------
__global__ __launch_bounds__(256) void proj_k(
    const float* __restrict__ feat1,
    const float* __restrict__ cvw, const float* __restrict__ cvb,
    const float* __restrict__ pvw, const float* __restrict__ pvb2,
    const float* __restrict__ pqw, const float* __restrict__ pqb,
    const float* __restrict__ pkw, const float* __restrict__ pkb,
    unsigned short* __restrict__ vh, unsigned short* __restrict__ pvs,
    unsigned short* __restrict__ pq_t, unsigned short* __restrict__ pks) {
  const int b = blockIdx.z, g = blockIdx.y;
  const int p = blockIdx.x * 256 + threadIdx.x;
  const float* wbase; const float* bbase; int row0;
  if (g < 8)       { wbase = cvw; bbase = cvb;  row0 = g * 8; }
  else if (g < 16) { wbase = pvw; bbase = pvb2; row0 = (g - 8) * 8; }
  else if (g == 16){ wbase = pqw; bbase = pqb;  row0 = 0; }
  else             { wbase = pkw; bbase = pkb;  row0 = 0; }
  __shared__ float wsm[8][64];
  __shared__ float bs[8];
  for (int i = threadIdx.x; i < 512; i += 256) {
    const int j = i >> 6, ci = i & 63;
    wsm[j][ci] = wbase[(row0 + j) * C + ci];
  }
  if (threadIdx.x < 8) bs[threadIdx.x] = bbase[row0 + threadIdx.x];
  __syncthreads();
  float acc[8];
#pragma unroll
  for (int j = 0; j < 8; ++j) acc[j] = bs[j];
  const float* inb = feat1 + (size_t)b * C * N + p;
#pragma unroll 4
  for (int ci = 0; ci < C; ++ci) {
    const float v = inb[(size_t)ci * N];
#pragma unroll
    for (int j = 0; j < 8; ++j) acc[j] = fmaf(wsm[j][ci], v, acc[j]);
  }
  if (g < 8) {
    H8U h;
#pragma unroll
    for (int j = 0; j < 8; ++j) h.s[j] = f2bf(acc[j]);
    *(uint4*)&vh[(size_t)(b * N + p) * C + g * 8] = *(uint4*)&h;
  } else if (g < 16) {
    const int mt = p >> 5, r = p & 31, quadv = r >> 3, i = r & 7;
#pragma unroll
    for (int j = 0; j < 8; ++j) {
      const int c = (g - 8) * 8 + j, t4 = c >> 4, l15 = c & 15;
      const int lane = (quadv << 4) | l15;
      pvs[(size_t)(((b * NMT_G + mt) * 4 + t4) * 64 + lane) * 8 + i] = f2bf(acc[j]);
    }
  } else if (g == 16) {
    H8U h;
#pragma unroll
    for (int j = 0; j < 8; ++j) h.s[j] = f2bf(acc[j]);
    *(uint4*)&pq_t[(size_t)(b * N + p) * 8] = *(uint4*)&h;
  } else {
    const int mt = p >> 5, r = p & 31, rr = r & 7;
    const int pos = (rr < 4) ? ((r >> 3) * 4 + rr) : (16 + (r >> 3) * 4 + (rr - 4));
    H8U h;
#pragma unroll
    for (int j = 0; j < 8; ++j) h.s[j] = f2bf(acc[j]);
    *(uint4*)&pks[(size_t)((b * NMT_G + mt) * 32 + pos) * 8] = *(uint4*)&h;
  }
}

// ---------------- CAM attention fused: energy partials (8 waves) + softmax -> bf16 -------
__global__ __launch_bounds__(512) void cam_attn_k(const float* __restrict__ qT,
                                                  const float* __restrict__ kT,
                                                  unsigned short* __restrict__ attn_h) {
  const int b = blockIdx.y, c = blockIdx.x;
  const int w = threadIdx.x >> 6, d = threadIdx.x & 63;
  const int n0 = w * (NQ / 8);
  const float* qp = qT + ((size_t)b * NQ + n0) * C + c;
  const float* kp = kT + ((size_t)b * NQ + n0) * C + d;
  float s0 = 0.f, s1 = 0.f, s2 = 0.f, s3 = 0.f;
  for (int n = 0; n < NQ / 8; n += 4) {
    s0 = fmaf(qp[(n + 0) * C], kp[(n + 0) * C], s0);
    s1 = fmaf(qp[(n + 1) * C], kp[(n + 1) * C], s1);
    s2 = fmaf(qp[(n + 2) * C], kp[(n + 2) * C], s2);
    s3 = fmaf(qp[(n + 3) * C], kp[(n + 3) * C], s3);
  }
  __shared__ float es[8][C];
  es[w][d] = (s0 + s1) + (s2 + s3);
  __syncthreads();
  if (w == 0) {
    float e = 0.f;
#pragma unroll
    for (int i = 0; i < 8; ++i) e += es[i][d];
    float rmax = e;
#pragma unroll
    for (int m = 1; m < 64; m <<= 1) rmax = fmaxf(rmax, __shfl_xor(rmax, m));
    const float e2 = rmax - e;
    float m2 = e2;
#pragma unroll
    for (int m = 1; m < 64; m <<= 1) m2 = fmaxf(m2, __shfl_xor(m2, m));
    const float pexp = __expf(e2 - m2);
    float ssum = pexp;
#pragma unroll
    for (int m = 1; m < 64; m <<= 1) ssum += __shfl_xor(ssum, m);
    attn_h[((size_t)b * C + c) * C + d] = f2bf(pexp / ssum);
  }
}

// ---------------- PAM flash v7: coalesced frag loads, packed fragment-major C-store ------
__global__ __launch_bounds__(64) void pam_flash_k(
    const unsigned short* __restrict__ pq_t, const unsigned short* __restrict__ pks,
    const unsigned short* __restrict__ pvs,
    unsigned* __restrict__ scpf, float* __restrict__ Lp) {
  const int b = blockIdx.z, mc = blockIdx.y, nt = blockIdx.x;  // nt < 200
  const int lane = threadIdx.x;
  const int ln15 = lane & 15, quad = lane >> 4;
  const int nb = nt * 32;   // wave covers 32 n

  const unsigned short* pqt = pq_t + (size_t)b * N * 8;
  const unsigned short* pksb = pks + (size_t)b * NMT_G * 256;
  const unsigned short* pvsb = pvs + (size_t)b * NMT_G * 2048;

  U4H8 qf[2];
  qf[0].u = make_uint4(0, 0, 0, 0);
  qf[1].u = make_uint4(0, 0, 0, 0);
  if (quad == 0) {
    qf[0].u = *(const uint4*)&pqt[(size_t)(nb + ln15) * 8];
    qf[1].u = *(const uint4*)&pqt[(size_t)(nb + 16 + ln15) * 8];
  }

  f32x4 acc[2][4];
#pragma unroll
  for (int ns = 0; ns < 2; ++ns)
#pragma unroll
    for (int i = 0; i < 4; ++i) acc[ns][i] = (f32x4){0.f, 0.f, 0.f, 0.f};
  float l_run[2] = {0.f, 0.f};
  const f32x4 zf = {0.f, 0.f, 0.f, 0.f};

  U4H8 akA0, akA1, akB0, akB1, afA[4], afB[4];
  akA0.u = make_uint4(0, 0, 0, 0); akA1.u = make_uint4(0, 0, 0, 0);
  akB0.u = make_uint4(0, 0, 0, 0); akB1.u = make_uint4(0, 0, 0, 0);

  auto prefetch = [&](int gmt, U4H8& a0, U4H8& a1, U4H8* af) {
    if (quad == 0) {
      const unsigned short* tb = pksb + (size_t)gmt * 256;
      a0.u = *(const uint4*)&tb[ln15 * 8];
      a1.u = *(const uint4*)&tb[128 + ln15 * 8];
    }
    const unsigned short* vb_ = pvsb + (size_t)gmt * 2048 + lane * 8;
#pragma unroll
    for (int t4 = 0; t4 < 4; ++t4) af[t4].u = *(const uint4*)&vb_[t4 * 512];
  };
  auto compute = [&](const U4H8& a0, const U4H8& a1, const U4H8* af) {
#pragma unroll
    for (int ns = 0; ns < 2; ++ns) {
      f32x4 s0 = __builtin_amdgcn_mfma_f32_16x16x32_bf16(a0.h, qf[ns].h, zf, 0, 0, 0);
      f32x4 s1 = __builtin_amdgcn_mfma_f32_16x16x32_bf16(a1.h, qf[ns].h, zf, 0, 0, 0);
      const float e0 = __expf(s0.x), e1 = __expf(s0.y);
      const float e2 = __expf(s0.z), e3 = __expf(s0.w);
      const float e4 = __expf(s1.x), e5 = __expf(s1.y);
      const float e6 = __expf(s1.z), e7 = __expf(s1.w);
      l_run[ns] += ((e0 + e1) + (e2 + e3)) + ((e4 + e5) + (e6 + e7));
      WBU wb;
      wb.h2[0] = __float22bfloat162_rn(make_float2(e0, e1));
      wb.h2[1] = __float22bfloat162_rn(make_float2(e2, e3));
      wb.h2[2] = __float22bfloat162_rn(make_float2(e4, e5));
      wb.h2[3] = __float22bfloat162_rn(make_float2(e6, e7));
#pragma unroll
      for (int t4 = 0; t4 < 4; ++t4)
        acc[ns][t4] = __builtin_amdgcn_mfma_f32_16x16x32_bf16(af[t4].h, wb.h, acc[ns][t4], 0, 0, 0);
    }
  };

  constexpr int NMT = MCH / 32;  // 25
  const int gmt0 = mc * NMT;
  prefetch(gmt0, akA0, akA1, afA);
  int mt = 0;
  for (; mt + 2 <= NMT; mt += 2) {
    prefetch(gmt0 + mt + 1, akB0, akB1, afB);
    compute(akA0, akA1, afA);
    if (mt + 2 < NMT) prefetch(gmt0 + mt + 2, akA0, akA1, afA);
    compute(akB0, akB1, afB);
  }
  if (mt < NMT) compute(akA0, akA1, afA);  // NMT odd: last tile is in A

#pragma unroll
  for (int ns = 0; ns < 2; ++ns) {
    float lt = l_run[ns];
    lt += __shfl_xor(lt, 16);
    lt += __shfl_xor(lt, 32);
    if (quad == 0) Lp[(size_t)mc * (B * N) + (size_t)b * N + nb + ns * 16 + ln15] = lt;
  }
  unsigned* outp = scpf + ((size_t)((mc * B + b) * NTC + nt)) * 16 * 64 + lane;
#pragma unroll
  for (int ns = 0; ns < 2; ++ns)
#pragma unroll
    for (int t4 = 0; t4 < 4; ++t4) {
      outp[(size_t)(ns * 8 + t4 * 2 + 0) * 64] = pack2(acc[ns][t4].x, acc[ns][t4].y);
      outp[(size_t)(ns * 8 + t4 * 2 + 1) * 64] = pack2(acc[ns][t4].z, acc[ns][t4].w);
    }
}

// ---------------- combine v3: MFMA attn@v + frag scp + merge + bf16 NHWC fsum + stats ----
__global__ __launch_bounds__(64) void combine_k(
    const unsigned short* __restrict__ attn_h, const unsigned short* __restrict__ vh,
    const unsigned short* __restrict__ feat1h, const unsigned* __restrict__ scpf,
    const float* __restrict__ Lp, const float* __restrict__ g1, const float* __restrict__ g2,
    unsigned short* __restrict__ fsumh, float* __restrict__ part2) {
  const int b = blockIdx.y, nt = blockIdx.x;  // 200 tiles of 32 px
  const int lane = threadIdx.x, ln15 = lane & 15, quad = lane >> 4;
  const int nb = nt * 32;
  const float g1v = g1[0], g2v = g2[0];

  const unsigned short* ab = attn_h + (size_t)b * C * C;
  U4H8 afr[4][2];
#pragma unroll
  for (int t4 = 0; t4 < 4; ++t4)
#pragma unroll
    for (int kc = 0; kc < 2; ++kc)
      afr[t4][kc].u = *(const uint4*)&ab[(size_t)(t4 * 16 + ln15) * C + kc * 32 + quad * 8];

  f32x4 acc[2][4];
#pragma unroll
  for (int ns = 0; ns < 2; ++ns)
#pragma unroll
    for (int i = 0; i < 4; ++i) acc[ns][i] = (f32x4){0.f, 0.f, 0.f, 0.f};
  const unsigned short* vbh = vh + (size_t)b * N * C;
#pragma unroll
  for (int ns = 0; ns < 2; ++ns)
#pragma unroll
    for (int kc = 0; kc < 2; ++kc) {
      U4H8 bfr;
      bfr.u = *(const uint4*)&vbh[(size_t)(nb + ns * 16 + ln15) * C + kc * 32 + quad * 8];
#pragma unroll
      for (int t4 = 0; t4 < 4; ++t4)
        acc[ns][t4] = __builtin_amdgcn_mfma_f32_16x16x32_bf16(afr[t4][kc].h, bfr.h, acc[ns][t4], 0, 0, 0);
    }

  float sc[2][4][4];
#pragma unroll
  for (int ns = 0; ns < 2; ++ns)
#pragma unroll
    for (int t4 = 0; t4 < 4; ++t4)
#pragma unroll
      for (int r = 0; r < 4; ++r) sc[ns][t4][r] = 0.f;
#pragma unroll
  for (int s = 0; s < SAP; ++s) {
    const unsigned* sp = scpf + ((size_t)((s * B + b) * NTC + nt)) * 16 * 64 + lane;
#pragma unroll
    for (int ns = 0; ns < 2; ++ns)
#pragma unroll
      for (int t4 = 0; t4 < 4; ++t4) {
        const unsigned u0 = sp[(size_t)(ns * 8 + t4 * 2 + 0) * 64];
        const unsigned u1 = sp[(size_t)(ns * 8 + t4 * 2 + 1) * 64];
        sc[ns][t4][0] += bf2f((unsigned short)(u0 & 0xffffu));
        sc[ns][t4][1] += bf2f((unsigned short)(u0 >> 16));
        sc[ns][t4][2] += bf2f((unsigned short)(u1 & 0xffffu));
        sc[ns][t4][3] += bf2f((unsigned short)(u1 >> 16));
      }
  }
  float invL[2];
#pragma unroll
  for (int ns = 0; ns < 2; ++ns) {
    const int px = nb + ns * 16 + ln15;
    float L = 0.f;
#pragma unroll
    for (int s = 0; s < SAP; ++s) L += Lp[(size_t)s * (B * N) + b * N + px];
    invL[ns] = 1.f / L;
  }

  float ssum_r[4][4], ssq_r[4][4];
#pragma unroll
  for (int t4 = 0; t4 < 4; ++t4)
#pragma unroll
    for (int r = 0; r < 4; ++r) { ssum_r[t4][r] = 0.f; ssq_r[t4][r] = 0.f; }

#pragma unroll
  for (int ns = 0; ns < 2; ++ns) {
    const int px = nb + ns * 16 + ln15;
    const unsigned short* fh = feat1h + (size_t)(b * N + px) * C;
    unsigned short* fo = fsumh + (size_t)(b * N + px) * C;
#pragma unroll
    for (int t4 = 0; t4 < 4; ++t4) {
      const ushort4 f4 = *(const ushort4*)&fh[t4 * 16 + quad * 4];
      const float sa[4] = {acc[ns][t4].x, acc[ns][t4].y, acc[ns][t4].z, acc[ns][t4].w};
      float v[4];
#pragma unroll
      for (int r = 0; r < 4; ++r) {
        const float res = bf2f(((const unsigned short*)&f4)[r]);
        v[r] = fmaf(g1v, sa[r], fmaf(g2v, sc[ns][t4][r] * invL[ns], res));
        ssum_r[t4][r] += v[r];
        ssq_r[t4][r] = fmaf(v[r], v[r], ssq_r[t4][r]);
      }
      uint2 ua;
      ua.x = pack2(v[0], v[1]);
      ua.y = pack2(v[2], v[3]);
      *(uint2*)&fo[t4 * 16 + quad * 4] = ua;
    }
  }
  const int bid = b * NTC + nt;
#pragma unroll
  for (int t4 = 0; t4 < 4; ++t4)
#pragma unroll
    for (int r = 0; r < 4; ++r) {
      float s = ssum_r[t4][r], q = ssq_r[t4][r];
#pragma unroll
      for (int o = 1; o < 16; o <<= 1) {
        s += __shfl_xor(s, o);
        q += __shfl_xor(q, o);
      }
      if (ln15 == 0) {
        const int c = t4 * 16 + quad * 4 + r;
        part2[(size_t)c * (B * NTC) + bid] = s;
        part2[(size_t)(64 + c) * (B * NTC) + bid] = q;
      }
    }
}

// ---------------- BN2: fused reduce + apply -> x2t bf16 NHWC (fsum is bf16 NHWC) ---------
__global__ __launch_bounds__(256) void bn2_nhwc_k(
    const unsigned short* __restrict__ fsumh, const float* __restrict__ part2,
    const float* __restrict__ g, const float* __restrict__ bt,
    unsigned short* __restrict__ out) {
  __shared__ float sc_s[C], sh_s[C], raw[128];
  reduce_stats(part2, B * NTC, g, bt, sc_s, sh_s, raw);
  const int idx = blockIdx.x * 256 + threadIdx.x;  // b*N+p
  const unsigned short* ip = fsumh + (size_t)idx * C;
#pragma unroll
  for (int j = 0; j < 8; ++j) {
    H8U in;
    *(uint4*)&in = *(const uint4*)&ip[j * 8];
    H8U v;
#pragma unroll
    for (int i = 0; i < 8; ++i) {
      const int c = j * 8 + i;
      v.s[i] = f2bf(fmaf(bf2f(in.s[i]), sc_s[c], sh_s[c]));
    }
    *(uint4*)&out[(size_t)idx * C + j * 8] = *(uint4*)&v;
  }
}

// ---------------- BN3: fused reduce + apply + relu -> final out (NCHW fp32) -------------
__global__ __launch_bounds__(256) void bn3_apply_k(
    const float* __restrict__ y3, const float* __restrict__ part,
    const float* __restrict__ g, const float* __restrict__ bt,
    float* __restrict__ out) {
  __shared__ float sc_s[C], sh_s[C], raw[128];
  reduce_stats(part, B * NT3, g, bt, sc_s, sh_s, raw);
  const int idx = blockIdx.x * 256 + threadIdx.x;  // b*N+p
  const int b = idx / N, p = idx - b * N;
  const float* ip = y3 + (size_t)b * C * N + p;
  float* op = out + (size_t)b * C * N + p;
#pragma unroll 8
  for (int c = 0; c < C; ++c)
    op[(size_t)c * N] = fmaxf(fmaf(ip[(size_t)c * N], sc_s[c], sh_s[c]), 0.f);
}

}  // namespace

extern "C" void kernel_launch(void* const* d_in, const int* in_sizes, int n_in,
                              void* d_out, int out_size, void* d_ws, size_t ws_size,
                              hipStream_t stream) {
  (void)in_sizes; (void)n_in; (void)out_size; (void)ws_size;
  const float* x    = (const float*)d_in[0];
  const float* Wc   = (const float*)d_in[1];
  const float* bn1g = (const float*)d_in[2];
  const float* bn1b = (const float*)d_in[3];
  const float* cqw  = (const float*)d_in[4];
  const float* cqb  = (const float*)d_in[5];
  const float* ckw  = (const float*)d_in[6];
  const float* ckb  = (const float*)d_in[7];
  const float* cvw  = (const float*)d_in[8];
  const float* cvb  = (const float*)d_in[9];
  const float* pqw  = (const float*)d_in[10];
  const float* pqb  = (const float*)d_in[11];
  const float* pkw  = (const float*)d_in[12];
  const float* pkb  = (const float*)d_in[13];
  const float* pvw  = (const float*)d_in[14];
  const float* pvb  = (const float*)d_in[15];
  const float* g1   = (const float*)d_in[16];
  const float* g2   = (const float*)d_in[17];
  const float* bn2g = (const float*)d_in[18];
  const float* bn2b = (const float*)d_in[19];
  const float* Wd   = (const float*)d_in[20];
  const float* bn3g = (const float*)d_in[21];
  const float* bn3b = (const float*)d_in[22];
  float* out = (float*)d_out;

  float* wsp = (float*)d_ws;
  size_t off = 0;
  auto alloc = [&](size_t nel) { float* p = wsp + off; off += nel; return p; };
  float* feat1 = alloc((size_t)B * C * N);
  float* y1    = alloc((size_t)B * C * N);
  float* qT    = alloc((size_t)B * NQ * C);
  float* kT    = alloc((size_t)B * NQ * C);
  unsigned short* vh   = (unsigned short*)alloc((size_t)B * N * C / 2);
  unsigned short* attn_h = (unsigned short*)alloc((size_t)B * C * C / 2 + 32);
  unsigned short* pvs  = (unsigned short*)alloc((size_t)B * C * N / 2);
  unsigned short* pq_t = (unsigned short*)alloc((size_t)B * N * 4);
  unsigned short* pks  = (unsigned short*)alloc((size_t)B * N * 4);
  unsigned* scpf = (unsigned*)alloc((size_t)SAP * B * NTC * 16 * 64);
  float* Lp    = alloc((size_t)SAP * B * N);
  unsigned short* fsumh = (unsigned short*)alloc((size_t)B * N * C / 2);  // bf16 NHWC
  float* y3    = alloc((size_t)B * C * N);
  float* part  = alloc((size_t)128 * B * NT3);
  float* part2 = alloc((size_t)128 * B * NTC);
  unsigned short* xt     = (unsigned short*)alloc((size_t)B * N * C / 2);
  unsigned short* feat1h = (unsigned short*)alloc((size_t)B * N * C / 2);
  unsigned short* x2t    = (unsigned short*)alloc((size_t)B * N * C / 2);
  unsigned short* w9c = (unsigned short*)alloc((size_t)9 * C * C / 2);
  unsigned short* w9d = (unsigned short*)alloc((size_t)9 * C * C / 2);
  unsigned short* w4q = (unsigned short*)alloc((size_t)4 * C * C / 2);
  unsigned short* w4k = (unsigned short*)alloc((size_t)4 * C * C / 2);

  // 1. weight transforms + x->NHWC (merged)
  xform_k<<<dim3(144, 5), 256, 0, stream>>>(x, Wc, Wd, cqw, ckw, xt, w9c, w9d, w4q, w4k);
  // 2. conv_c (+stats partials)
  conv3x3_mfma_k<<<dim3(NT3, B), 256, 0, stream>>>(xt, w9c, y1, part);
  // 3. bn1 (fused reduce) -> feat1 fp32 NCHW + feat1h bf16 NHWC
  bn1_apply_k<<<dim3(B * N / 256), 256, 0, stream>>>(y1, part, bn1g, bn1b, feat1, feat1h);
  // 4-5. CAM q/k conv + 1x1 projections
  conv2x2_mfma_k<<<dim3(NQ / 16, B), 64, 0, stream>>>(feat1h, w4q, cqb, w4k, ckb, qT, kT);
  proj_k<<<dim3(N / 256, 18, B), 256, 0, stream>>>(feat1, cvw, cvb, pvw, pvb, pqw, pqb,
                                                   pkw, pkb, vh, pvs, pq_t, pks);
  // 6. CAM attention
  cam_attn_k<<<dim3(C, B), 512, 0, stream>>>(qT, kT, attn_h);
  // 7. PAM flash attention
  pam_flash_k<<<dim3(NTC, SAP, B), 64, 0, stream>>>(pq_t, pks, pvs, scpf, Lp);
  // 8. combine (MFMA attn@v + merge + residual) -> fsumh bf16 NHWC + stats partials
  combine_k<<<dim3(NTC, B), 64, 0, stream>>>(attn_h, vh, feat1h, scpf, Lp, g1, g2,
                                             fsumh, part2);
  // 9. bn2 (fused reduce) -> x2t bf16 NHWC
  bn2_nhwc_k<<<dim3(B * N / 256), 256, 0, stream>>>(fsumh, part2, bn2g, bn2b, x2t);
  // 10. conv_d (+stats partials)
  conv3x3_mfma_k<<<dim3(NT3, B), 256, 0, stream>>>(x2t, w9d, y3, part);
  // 11. bn3 (fused reduce) + relu -> out
  bn3_apply_k<<<dim3(B * N / 256), 256, 0, stream>>>(y3, part, bn3g, bn3b, out);
}

// Round 12
// 219.737 us; speedup vs baseline: 1.0821x; 1.0821x over previous
//
#include <hip/hip_runtime.h>
#include <hip/hip_bf16.h>
#include <math.h>

namespace {

constexpr int B = 2, C = 64, H = 80, W = 80, N = H * W;  // N = 6400
constexpr int NQ = 1600;   // 40*40
constexpr float EPS = 1e-5f;
constexpr int SAP = 8;           // pam flash m-chunks
constexpr int MCH = N / SAP;     // 800 m per chunk
constexpr int NMT_G = N / 32;    // 200 global m-tiles of 32
constexpr int NT3 = 400;         // conv3x3 pixel tiles (16 px each)
constexpr int NTP = 100;         // pam pixel tiles (64 px each)
constexpr int NTC = 200;         // combine pixel tiles (32 px each)
constexpr float INV_BN = 1.0f / (float)(B * N);

typedef __attribute__((ext_vector_type(8))) short bf16x8;
typedef __attribute__((ext_vector_type(4))) float f32x4;

union U4H8 { uint4 u; bf16x8 h; };
union H8U { unsigned short s[8]; bf16x8 h; };
union WBU { __hip_bfloat162 h2[4]; bf16x8 h; };

__device__ __forceinline__ unsigned short f2bf(float x) {
  unsigned u = __builtin_bit_cast(unsigned, x);
  u += 0x7fffu + ((u >> 16) & 1u);   // RNE (no NaN inputs here)
  return (unsigned short)(u >> 16);
}
__device__ __forceinline__ float bf2f(unsigned short s) {
  return __builtin_bit_cast(float, (unsigned)s << 16);
}
__device__ __forceinline__ unsigned pack2(float x, float y) {
  return (unsigned)f2bf(x) | ((unsigned)f2bf(y) << 16);
}

// ---------------- merged: weight transforms (y<4) + x NCHW->NHWC bf16 (y==4) ------------
__global__ void xform_k(const float* __restrict__ x,
                        const float* __restrict__ Wc, const float* __restrict__ Wd,
                        const float* __restrict__ cqw, const float* __restrict__ ckw,
                        unsigned short* __restrict__ xt,
                        unsigned short* __restrict__ w9c, unsigned short* __restrict__ w9d,
                        unsigned short* __restrict__ w4q, unsigned short* __restrict__ w4k) {
  const int z = blockIdx.y;
  if (z < 4) {
    const int taps = (z < 2) ? 9 : 4;
    const float* src = (z == 0) ? Wc : (z == 1) ? Wd : (z == 2) ? cqw : ckw;
    unsigned short* dst = (z == 0) ? w9c : (z == 1) ? w9d : (z == 2) ? w4q : w4k;
    const int n = C * C * taps;
    const int i = blockIdx.x * 256 + threadIdx.x;
    if (i >= n) return;
    const int co = i / (C * taps), rem = i - co * (C * taps);
    const int ci = rem / taps, kk = rem - ci * taps;
    dst[(size_t)kk * (C * C) + co * C + ci] = f2bf(src[i]);
  } else {
    if (blockIdx.x >= B * N / 256) return;
    const int idx = blockIdx.x * 256 + threadIdx.x;  // b*N+p
    const int b = idx / N, p = idx - b * N;
    const float* ip = x + (size_t)b * C * N + p;
#pragma unroll
    for (int j = 0; j < 8; ++j) {
      H8U v;
#pragma unroll
      for (int i = 0; i < 8; ++i) v.s[i] = f2bf(ip[(size_t)(j * 8 + i) * N]);
      *(uint4*)&xt[(size_t)idx * C + j * 8] = *(uint4*)&v;
    }
  }
}

// ---------------- conv 3x3 pad 1 via implicit-GEMM MFMA, co split 4 ways ----------------
__global__ __launch_bounds__(256) void conv3x3_mfma_k(
    const unsigned short* __restrict__ in_t, const unsigned short* __restrict__ wt,
    float* __restrict__ out, float* __restrict__ part) {
  const int b = blockIdx.y, tile = blockIdx.x;  // 400 tiles of 16 pixels (within-row)
  const int wv = threadIdx.x >> 6;              // co-group
  const int lane = threadIdx.x & 63, ln15 = lane & 15, quad = lane >> 4;
  const int h = tile / 5, wbase = (tile - h * 5) * 16;
  const int w0 = wbase + ln15;
  const unsigned short* itb = in_t + (size_t)b * N * C;

  f32x4 acc = (f32x4){0.f, 0.f, 0.f, 0.f};

#pragma unroll
  for (int dh = -1; dh <= 1; ++dh) {
    const int hh = h + dh;
    if ((unsigned)hh >= (unsigned)H) continue;  // wave-uniform
#pragma unroll
    for (int dw = -1; dw <= 1; ++dw) {
      const bool valid = (unsigned)(w0 + dw) < (unsigned)W;
      const int pp = hh * W + (valid ? w0 + dw : w0);
      const uint4* bp = (const uint4*)(itb + (size_t)pp * C);
      U4H8 b0, b1;
      b0.u = bp[quad];
      b1.u = bp[4 + quad];
      if (!valid) { b0.u = make_uint4(0, 0, 0, 0); b1.u = make_uint4(0, 0, 0, 0); }
      const int kk = (dh + 1) * 3 + (dw + 1);
      const uint4* wp = (const uint4*)(wt + (size_t)kk * (C * C));
      U4H8 a0, a1;
      a0.u = wp[(wv * 16 + ln15) * 8 + quad];
      a1.u = wp[(wv * 16 + ln15) * 8 + 4 + quad];
      acc = __builtin_amdgcn_mfma_f32_16x16x32_bf16(a0.h, b0.h, acc, 0, 0, 0);
      acc = __builtin_amdgcn_mfma_f32_16x16x32_bf16(a1.h, b1.h, acc, 0, 0, 0);
    }
  }
  const int p = h * W + w0;
  float* ob = out + (size_t)b * C * N + p;
  const int cobase = wv * 16 + quad * 4;
  ob[(size_t)(cobase + 0) * N] = acc.x;
  ob[(size_t)(cobase + 1) * N] = acc.y;
  ob[(size_t)(cobase + 2) * N] = acc.z;
  ob[(size_t)(cobase + 3) * N] = acc.w;
  // per-channel partial stats over the 16 pixels; plain stores (no contention)
  const int bid = b * NT3 + tile;
  float v[4] = {acc.x, acc.y, acc.z, acc.w};
#pragma unroll
  for (int r = 0; r < 4; ++r) {
    float s = v[r], q = v[r] * v[r];
#pragma unroll
    for (int o = 1; o < 16; o <<= 1) {
      s += __shfl_xor(s, o);
      q += __shfl_xor(q, o);
    }
    if (ln15 == 0) {
      const int co = cobase + r;
      part[(size_t)co * (B * NT3) + bid] = s;
      part[(size_t)(64 + co) * (B * NT3) + bid] = q;
    }
  }
}

// ---------------- reduce partials: stats[j] = sum_i part[j][i], j < 128 -------------
__global__ __launch_bounds__(256) void bn_reduce_k(const float* __restrict__ part,
                                                   float* __restrict__ stats, int n) {
  const int j = blockIdx.x;
  float s = 0.f;
  for (int i = threadIdx.x; i < n; i += 256) s += part[(size_t)j * n + i];
#pragma unroll
  for (int o = 1; o < 64; o <<= 1) s += __shfl_xor(s, o);
  __shared__ float rs[4];
  if ((threadIdx.x & 63) == 0) rs[threadIdx.x >> 6] = s;
  __syncthreads();
  if (threadIdx.x == 0) stats[j] = rs[0] + rs[1] + rs[2] + rs[3];
}

// ---------------- BN1 apply + relu -> feat1 (fp32 NCHW) + feat1h (bf16 NHWC) ------------
__global__ void bn1_apply_k(const float* __restrict__ y, const float* __restrict__ ssum,
                            const float* __restrict__ ssq, const float* __restrict__ g,
                            const float* __restrict__ bt, float* __restrict__ feat1,
                            unsigned short* __restrict__ feat1h) {
  __shared__ float sc_s[C], sh_s[C];
  if (threadIdx.x < C) {
    const int c = threadIdx.x;
    const float m = ssum[c] * INV_BN;
    const float var = ssq[c] * INV_BN - m * m;
    const float sc = rsqrtf(var + EPS) * g[c];
    sc_s[c] = sc;
    sh_s[c] = bt[c] - m * sc;
  }
  __syncthreads();
  const int idx = blockIdx.x * 256 + threadIdx.x;  // b*N+p
  const int b = idx / N, p = idx - b * N;
  const float* ip = y + (size_t)b * C * N + p;
  float* fp = feat1 + (size_t)b * C * N + p;
#pragma unroll
  for (int j = 0; j < 8; ++j) {
    H8U v;
#pragma unroll
    for (int i = 0; i < 8; ++i) {
      const int c = j * 8 + i;
      const float val = fmaxf(fmaf(ip[(size_t)c * N], sc_s[c], sh_s[c]), 0.f);
      fp[(size_t)c * N] = val;
      v.s[i] = f2bf(val);
    }
    *(uint4*)&feat1h[(size_t)idx * C + j * 8] = *(uint4*)&v;
  }
}

// ---------------- conv 2x2 stride 2 via MFMA, q & k in one wave, transposed out ----------
__global__ __launch_bounds__(64) void conv2x2_mfma_k(
    const unsigned short* __restrict__ feat1h,
    const unsigned short* __restrict__ w4q, const float* __restrict__ cqb,
    const unsigned short* __restrict__ w4k, const float* __restrict__ ckb,
    float* __restrict__ qT, float* __restrict__ kT) {
  const int b = blockIdx.y, tile = blockIdx.x;  // 100 tiles of 16 output px
  const int lane = threadIdx.x, ln15 = lane & 15, quad = lane >> 4;
  const int p = tile * 16 + ln15;               // 0..1599
  const int oh = p / 40, ow = p - oh * 40;
  const int pin = (oh * 2) * W + ow * 2;
  const unsigned short* itb = feat1h + (size_t)b * N * C;

  f32x4 aq[4], ak[4];
#pragma unroll
  for (int i = 0; i < 4; ++i) { aq[i] = (f32x4){0.f,0.f,0.f,0.f}; ak[i] = (f32x4){0.f,0.f,0.f,0.f}; }

#pragma unroll
  for (int dt = 0; dt < 4; ++dt) {
    const int dh = dt >> 1, dw = dt & 1;
    const uint4* bp = (const uint4*)(itb + (size_t)(pin + dh * W + dw) * C);
    U4H8 b0, b1;
    b0.u = bp[quad];
    b1.u = bp[4 + quad];
    const uint4* wq = (const uint4*)(w4q + (size_t)dt * (C * C));
    const uint4* wk = (const uint4*)(w4k + (size_t)dt * (C * C));
#pragma unroll
    for (int t4 = 0; t4 < 4; ++t4) {
      U4H8 a0, a1;
      a0.u = wq[(t4 * 16 + ln15) * 8 + quad];
      a1.u = wq[(t4 * 16 + ln15) * 8 + 4 + quad];
      aq[t4] = __builtin_amdgcn_mfma_f32_16x16x32_bf16(a0.h, b0.h, aq[t4], 0, 0, 0);
      aq[t4] = __builtin_amdgcn_mfma_f32_16x16x32_bf16(a1.h, b1.h, aq[t4], 0, 0, 0);
      a0.u = wk[(t4 * 16 + ln15) * 8 + quad];
      a1.u = wk[(t4 * 16 + ln15) * 8 + 4 + quad];
      ak[t4] = __builtin_amdgcn_mfma_f32_16x16x32_bf16(a0.h, b0.h, ak[t4], 0, 0, 0);
      ak[t4] = __builtin_amdgcn_mfma_f32_16x16x32_bf16(a1.h, b1.h, ak[t4], 0, 0, 0);
    }
  }
  float* qrow = qT + ((size_t)b * NQ + p) * C;
  float* krow = kT + ((size_t)b * NQ + p) * C;
#pragma unroll
  for (int t4 = 0; t4 < 4; ++t4) {
    const int co = t4 * 16 + quad * 4;
    const float4 bq = *(const float4*)&cqb[co];
    const float4 bk = *(const float4*)&ckb[co];
    *(float4*)&qrow[co] = make_float4(aq[t4].x + bq.x, aq[t4].y + bq.y,
                                      aq[t4].z + bq.z, aq[t4].w + bq.w);
    *(float4*)&krow[co] = make_float4(ak[t4].x + bk.x, ak[t4].y + bk.y,
                                      ak[t4].z + bk.z, ak[t4].w + bk.w);
  }
}

// ---------------- fused 1x1 projections, 8 co per block ----------------
__global__ __launch_bounds__(256) void proj_k(
    const float* __restrict__ feat1,
    const float* __restrict__ cvw, const float* __restrict__ cvb,
    const float* __restrict__ pvw, const float* __restrict__ pvb2,
    const float* __restrict__ pqw, const float* __restrict__ pqb,
    const float* __restrict__ pkw, const float* __restrict__ pkb,
    unsigned short* __restrict__ vh, unsigned short* __restrict__ pvs,
    unsigned short* __restrict__ pq_t, unsigned short* __restrict__ pks) {
  const int b = blockIdx.z, g = blockIdx.y;
  const int p = blockIdx.x * 256 + threadIdx.x;
  const float* wbase; const float* bbase; int row0;
  if (g < 8)       { wbase = cvw; bbase = cvb;  row0 = g * 8; }
  else if (g < 16) { wbase = pvw; bbase = pvb2; row0 = (g - 8) * 8; }
  else if (g == 16){ wbase = pqw; bbase = pqb;  row0 = 0; }
  else             { wbase = pkw; bbase = pkb;  row0 = 0; }
  __shared__ float wsm[8][64];
  __shared__ float bs[8];
  for (int i = threadIdx.x; i < 512; i += 256) {
    const int j = i >> 6, ci = i & 63;
    wsm[j][ci] = wbase[(row0 + j) * C + ci];
  }
  if (threadIdx.x < 8) bs[threadIdx.x] = bbase[row0 + threadIdx.x];
  __syncthreads();
  float acc[8];
#pragma unroll
  for (int j = 0; j < 8; ++j) acc[j] = bs[j];
  const float* inb = feat1 + (size_t)b * C * N + p;
#pragma unroll 4
  for (int ci = 0; ci < C; ++ci) {
    const float v = inb[(size_t)ci * N];
#pragma unroll
    for (int j = 0; j < 8; ++j) acc[j] = fmaf(wsm[j][ci], v, acc[j]);
  }
  if (g < 8) {
    H8U h;
#pragma unroll
    for (int j = 0; j < 8; ++j) h.s[j] = f2bf(acc[j]);
    *(uint4*)&vh[(size_t)(b * N + p) * C + g * 8] = *(uint4*)&h;
  } else if (g < 16) {
    const int mt = p >> 5, r = p & 31, quadv = r >> 3, i = r & 7;
#pragma unroll
    for (int j = 0; j < 8; ++j) {
      const int c = (g - 8) * 8 + j, t4 = c >> 4, l15 = c & 15;
      const int lane = (quadv << 4) | l15;
      pvs[(size_t)(((b * NMT_G + mt) * 4 + t4) * 64 + lane) * 8 + i] = f2bf(acc[j]);
    }
  } else if (g == 16) {
    H8U h;
#pragma unroll
    for (int j = 0; j < 8; ++j) h.s[j] = f2bf(acc[j]);
    *(uint4*)&pq_t[(size_t)(b * N + p) * 8] = *(uint4*)&h;
  } else {
    const int mt = p >> 5, r = p & 31, rr = r & 7;
    const int pos = (rr < 4) ? ((r >> 3) * 4 + rr) : (16 + (r >> 3) * 4 + (rr - 4));
    H8U h;
#pragma unroll
    for (int j = 0; j < 8; ++j) h.s[j] = f2bf(acc[j]);
    *(uint4*)&pks[(size_t)((b * NMT_G + mt) * 32 + pos) * 8] = *(uint4*)&h;
  }
}

// ---------------- CAM attention fused: energy partials (8 waves) + softmax -> bf16 -------
__global__ __launch_bounds__(512) void cam_attn_k(const float* __restrict__ qT,
                                                  const float* __restrict__ kT,
                                                  unsigned short* __restrict__ attn_h) {
  const int b = blockIdx.y, c = blockIdx.x;
  const int w = threadIdx.x >> 6, d = threadIdx.x & 63;
  const int n0 = w * (NQ / 8);
  const float* qp = qT + ((size_t)b * NQ + n0) * C + c;
  const float* kp = kT + ((size_t)b * NQ + n0) * C + d;
  float s0 = 0.f, s1 = 0.f, s2 = 0.f, s3 = 0.f;
  for (int n = 0; n < NQ / 8; n += 4) {
    s0 = fmaf(qp[(n + 0) * C], kp[(n + 0) * C], s0);
    s1 = fmaf(qp[(n + 1) * C], kp[(n + 1) * C], s1);
    s2 = fmaf(qp[(n + 2) * C], kp[(n + 2) * C], s2);
    s3 = fmaf(qp[(n + 3) * C], kp[(n + 3) * C], s3);
  }
  __shared__ float es[8][C];
  es[w][d] = (s0 + s1) + (s2 + s3);
  __syncthreads();
  if (w == 0) {
    float e = 0.f;
#pragma unroll
    for (int i = 0; i < 8; ++i) e += es[i][d];
    float rmax = e;
#pragma unroll
    for (int m = 1; m < 64; m <<= 1) rmax = fmaxf(rmax, __shfl_xor(rmax, m));
    const float e2 = rmax - e;
    float m2 = e2;
#pragma unroll
    for (int m = 1; m < 64; m <<= 1) m2 = fmaxf(m2, __shfl_xor(m2, m));
    const float pexp = __expf(e2 - m2);
    float ssum = pexp;
#pragma unroll
    for (int m = 1; m < 64; m <<= 1) ssum += __shfl_xor(ssum, m);
    attn_h[((size_t)b * C + c) * C + d] = f2bf(pexp / ssum);
  }
}

// ---------------- PAM flash v8: 64 n per wave (half the blocks, half the pv/pk re-reads) -
// scpf layout: [((mc*B+b)*100 + nt)*32 + e][lane] uints, e = ns*8+t4*2+pair (ns<4)
__global__ __launch_bounds__(64) void pam_flash_k(
    const unsigned short* __restrict__ pq_t, const unsigned short* __restrict__ pks,
    const unsigned short* __restrict__ pvs,
    unsigned* __restrict__ scpf, float* __restrict__ Lp) {
  const int b = blockIdx.z, mc = blockIdx.y, nt = blockIdx.x;  // nt < 100
  const int lane = threadIdx.x;
  const int ln15 = lane & 15, quad = lane >> 4;
  const int nb = nt * 64;   // wave covers 64 n

  const unsigned short* pqt = pq_t + (size_t)b * N * 8;
  const unsigned short* pksb = pks + (size_t)b * NMT_G * 256;
  const unsigned short* pvsb = pvs + (size_t)b * NMT_G * 2048;

  U4H8 qf[4];
#pragma unroll
  for (int ns = 0; ns < 4; ++ns) qf[ns].u = make_uint4(0, 0, 0, 0);
  if (quad == 0) {
#pragma unroll
    for (int ns = 0; ns < 4; ++ns)
      qf[ns].u = *(const uint4*)&pqt[(size_t)(nb + ns * 16 + ln15) * 8];
  }

  f32x4 acc[4][4];
#pragma unroll
  for (int ns = 0; ns < 4; ++ns)
#pragma unroll
    for (int i = 0; i < 4; ++i) acc[ns][i] = (f32x4){0.f, 0.f, 0.f, 0.f};
  float l_run[4] = {0.f, 0.f, 0.f, 0.f};
  const f32x4 zf = {0.f, 0.f, 0.f, 0.f};

  U4H8 akA0, akA1, akB0, akB1, afA[4], afB[4];
  akA0.u = make_uint4(0, 0, 0, 0); akA1.u = make_uint4(0, 0, 0, 0);
  akB0.u = make_uint4(0, 0, 0, 0); akB1.u = make_uint4(0, 0, 0, 0);

  auto prefetch = [&](int gmt, U4H8& a0, U4H8& a1, U4H8* af) {
    if (quad == 0) {
      const unsigned short* tb = pksb + (size_t)gmt * 256;
      a0.u = *(const uint4*)&tb[ln15 * 8];
      a1.u = *(const uint4*)&tb[128 + ln15 * 8];
    }
    const unsigned short* vb_ = pvsb + (size_t)gmt * 2048 + lane * 8;
#pragma unroll
    for (int t4 = 0; t4 < 4; ++t4) af[t4].u = *(const uint4*)&vb_[t4 * 512];
  };
  auto compute = [&](const U4H8& a0, const U4H8& a1, const U4H8* af) {
#pragma unroll
    for (int ns = 0; ns < 4; ++ns) {
      f32x4 s0 = __builtin_amdgcn_mfma_f32_16x16x32_bf16(a0.h, qf[ns].h, zf, 0, 0, 0);
      f32x4 s1 = __builtin_amdgcn_mfma_f32_16x16x32_bf16(a1.h, qf[ns].h, zf, 0, 0, 0);
      const float e0 = __expf(s0.x), e1 = __expf(s0.y);
      const float e2 = __expf(s0.z), e3 = __expf(s0.w);
      const float e4 = __expf(s1.x), e5 = __expf(s1.y);
      const float e6 = __expf(s1.z), e7 = __expf(s1.w);
      l_run[ns] += ((e0 + e1) + (e2 + e3)) + ((e4 + e5) + (e6 + e7));
      WBU wb;
      wb.h2[0] = __float22bfloat162_rn(make_float2(e0, e1));
      wb.h2[1] = __float22bfloat162_rn(make_float2(e2, e3));
      wb.h2[2] = __float22bfloat162_rn(make_float2(e4, e5));
      wb.h2[3] = __float22bfloat162_rn(make_float2(e6, e7));
#pragma unroll
      for (int t4 = 0; t4 < 4; ++t4)
        acc[ns][t4] = __builtin_amdgcn_mfma_f32_16x16x32_bf16(af[t4].h, wb.h, acc[ns][t4], 0, 0, 0);
    }
  };

  constexpr int NMT = MCH / 32;  // 25
  const int gmt0 = mc * NMT;
  prefetch(gmt0, akA0, akA1, afA);
  int mt = 0;
  for (; mt + 2 <= NMT; mt += 2) {
    prefetch(gmt0 + mt + 1, akB0, akB1, afB);
    compute(akA0, akA1, afA);
    if (mt + 2 < NMT) prefetch(gmt0 + mt + 2, akA0, akA1, afA);
    compute(akB0, akB1, afB);
  }
  if (mt < NMT) compute(akA0, akA1, afA);  // NMT odd: last tile is in A

#pragma unroll
  for (int ns = 0; ns < 4; ++ns) {
    float lt = l_run[ns];
    lt += __shfl_xor(lt, 16);
    lt += __shfl_xor(lt, 32);
    if (quad == 0) Lp[(size_t)mc * (B * N) + (size_t)b * N + nb + ns * 16 + ln15] = lt;
  }
  unsigned* outp = scpf + ((size_t)((mc * B + b) * NTP + nt)) * 32 * 64 + lane;
#pragma unroll
  for (int ns = 0; ns < 4; ++ns)
#pragma unroll
    for (int t4 = 0; t4 < 4; ++t4) {
      outp[(size_t)(ns * 8 + t4 * 2 + 0) * 64] = pack2(acc[ns][t4].x, acc[ns][t4].y);
      outp[(size_t)(ns * 8 + t4 * 2 + 1) * 64] = pack2(acc[ns][t4].z, acc[ns][t4].w);
    }
}

// ---------------- combine v3: MFMA attn@v + frag scp + merge + bf16 NHWC fsum + stats ----
__global__ __launch_bounds__(64) void combine_k(
    const unsigned short* __restrict__ attn_h, const unsigned short* __restrict__ vh,
    const unsigned short* __restrict__ feat1h, const unsigned* __restrict__ scpf,
    const float* __restrict__ Lp, const float* __restrict__ g1, const float* __restrict__ g2,
    unsigned short* __restrict__ fsumh, float* __restrict__ part2) {
  const int b = blockIdx.y, nt = blockIdx.x;  // 200 tiles of 32 px
  const int lane = threadIdx.x, ln15 = lane & 15, quad = lane >> 4;
  const int nb = nt * 32;
  const int nt64 = nt >> 1, half = nt & 1;   // pam tile mapping
  const float g1v = g1[0], g2v = g2[0];

  const unsigned short* ab = attn_h + (size_t)b * C * C;
  U4H8 afr[4][2];
#pragma unroll
  for (int t4 = 0; t4 < 4; ++t4)
#pragma unroll
    for (int kc = 0; kc < 2; ++kc)
      afr[t4][kc].u = *(const uint4*)&ab[(size_t)(t4 * 16 + ln15) * C + kc * 32 + quad * 8];

  f32x4 acc[2][4];
#pragma unroll
  for (int ns = 0; ns < 2; ++ns)
#pragma unroll
    for (int i = 0; i < 4; ++i) acc[ns][i] = (f32x4){0.f, 0.f, 0.f, 0.f};
  const unsigned short* vbh = vh + (size_t)b * N * C;
#pragma unroll
  for (int ns = 0; ns < 2; ++ns)
#pragma unroll
    for (int kc = 0; kc < 2; ++kc) {
      U4H8 bfr;
      bfr.u = *(const uint4*)&vbh[(size_t)(nb + ns * 16 + ln15) * C + kc * 32 + quad * 8];
#pragma unroll
      for (int t4 = 0; t4 < 4; ++t4)
        acc[ns][t4] = __builtin_amdgcn_mfma_f32_16x16x32_bf16(afr[t4][kc].h, bfr.h, acc[ns][t4], 0, 0, 0);
    }

  float sc[2][4][4];
#pragma unroll
  for (int ns = 0; ns < 2; ++ns)
#pragma unroll
    for (int t4 = 0; t4 < 4; ++t4)
#pragma unroll
      for (int r = 0; r < 4; ++r) sc[ns][t4][r] = 0.f;
#pragma unroll
  for (int s = 0; s < SAP; ++s) {
    const unsigned* sp = scpf + ((size_t)((s * B + b) * NTP + nt64)) * 32 * 64 + lane;
#pragma unroll
    for (int ns = 0; ns < 2; ++ns) {
      const int nsg = half * 2 + ns;
#pragma unroll
      for (int t4 = 0; t4 < 4; ++t4) {
        const unsigned u0 = sp[(size_t)(nsg * 8 + t4 * 2 + 0) * 64];
        const unsigned u1 = sp[(size_t)(nsg * 8 + t4 * 2 + 1) * 64];
        sc[ns][t4][0] += bf2f((unsigned short)(u0 & 0xffffu));
        sc[ns][t4][1] += bf2f((unsigned short)(u0 >> 16));
        sc[ns][t4][2] += bf2f((unsigned short)(u1 & 0xffffu));
        sc[ns][t4][3] += bf2f((unsigned short)(u1 >> 16));
      }
    }
  }
  float invL[2];
#pragma unroll
  for (int ns = 0; ns < 2; ++ns) {
    const int px = nb + ns * 16 + ln15;
    float L = 0.f;
#pragma unroll
    for (int s = 0; s < SAP; ++s) L += Lp[(size_t)s * (B * N) + b * N + px];
    invL[ns] = 1.f / L;
  }

  float ssum_r[4][4], ssq_r[4][4];
#pragma unroll
  for (int t4 = 0; t4 < 4; ++t4)
#pragma unroll
    for (int r = 0; r < 4; ++r) { ssum_r[t4][r] = 0.f; ssq_r[t4][r] = 0.f; }

#pragma unroll
  for (int ns = 0; ns < 2; ++ns) {
    const int px = nb + ns * 16 + ln15;
    const unsigned short* fh = feat1h + (size_t)(b * N + px) * C;
    unsigned short* fo = fsumh + (size_t)(b * N + px) * C;
#pragma unroll
    for (int t4 = 0; t4 < 4; ++t4) {
      const ushort4 f4 = *(const ushort4*)&fh[t4 * 16 + quad * 4];
      const float sa[4] = {acc[ns][t4].x, acc[ns][t4].y, acc[ns][t4].z, acc[ns][t4].w};
      float v[4];
#pragma unroll
      for (int r = 0; r < 4; ++r) {
        const float res = bf2f(((const unsigned short*)&f4)[r]);
        v[r] = fmaf(g1v, sa[r], fmaf(g2v, sc[ns][t4][r] * invL[ns], res));
        ssum_r[t4][r] += v[r];
        ssq_r[t4][r] = fmaf(v[r], v[r], ssq_r[t4][r]);
      }
      uint2 ua;
      ua.x = pack2(v[0], v[1]);
      ua.y = pack2(v[2], v[3]);
      *(uint2*)&fo[t4 * 16 + quad * 4] = ua;
    }
  }
  const int bid = b * NTC + nt;
#pragma unroll
  for (int t4 = 0; t4 < 4; ++t4)
#pragma unroll
    for (int r = 0; r < 4; ++r) {
      float s = ssum_r[t4][r], q = ssq_r[t4][r];
#pragma unroll
      for (int o = 1; o < 16; o <<= 1) {
        s += __shfl_xor(s, o);
        q += __shfl_xor(q, o);
      }
      if (ln15 == 0) {
        const int c = t4 * 16 + quad * 4 + r;
        part2[(size_t)c * (B * NTC) + bid] = s;
        part2[(size_t)(64 + c) * (B * NTC) + bid] = q;
      }
    }
}

// ---------------- BN2 apply -> x2t bf16 NHWC (fsum is bf16 NHWC) ----------------
__global__ void bn2_nhwc_k(const unsigned short* __restrict__ fsumh,
                           const float* __restrict__ ssum, const float* __restrict__ ssq,
                           const float* __restrict__ g, const float* __restrict__ bt,
                           unsigned short* __restrict__ out) {
  __shared__ float sc_s[C], sh_s[C];
  if (threadIdx.x < C) {
    const int c = threadIdx.x;
    const float m = ssum[c] * INV_BN;
    const float var = ssq[c] * INV_BN - m * m;
    const float sc = rsqrtf(var + EPS) * g[c];
    sc_s[c] = sc;
    sh_s[c] = bt[c] - m * sc;
  }
  __syncthreads();
  const int idx = blockIdx.x * 256 + threadIdx.x;  // b*N+p
  const unsigned short* ip = fsumh + (size_t)idx * C;
#pragma unroll
  for (int j = 0; j < 8; ++j) {
    H8U in;
    *(uint4*)&in = *(const uint4*)&ip[j * 8];
    H8U v;
#pragma unroll
    for (int i = 0; i < 8; ++i) {
      const int c = j * 8 + i;
      v.s[i] = f2bf(fmaf(bf2f(in.s[i]), sc_s[c], sh_s[c]));
    }
    *(uint4*)&out[(size_t)idx * C + j * 8] = *(uint4*)&v;
  }
}

// ---------------- BN3 apply + relu -> final out (per-channel blocks, 3200-way) ----------
__global__ void bn3_apply_k(const float* __restrict__ y, const float* __restrict__ ssum,
                            const float* __restrict__ ssq, const float* __restrict__ g,
                            const float* __restrict__ bt, float* __restrict__ out) {
  const int idx = blockIdx.x * 256 + threadIdx.x;
  const int c = (idx / N) % C;  // uniform per block (N % 256 == 0)
  __shared__ float sc_s, sh_s;
  if (threadIdx.x == 0) {
    const float m = ssum[c] * INV_BN;
    const float var = ssq[c] * INV_BN - m * m;
    const float sc = rsqrtf(var + EPS) * g[c];
    sc_s = sc;
    sh_s = bt[c] - m * sc;
  }
  __syncthreads();
  out[idx] = fmaxf(fmaf(y[idx], sc_s, sh_s), 0.f);
}

}  // namespace

extern "C" void kernel_launch(void* const* d_in, const int* in_sizes, int n_in,
                              void* d_out, int out_size, void* d_ws, size_t ws_size,
                              hipStream_t stream) {
  (void)in_sizes; (void)n_in; (void)out_size; (void)ws_size;
  const float* x    = (const float*)d_in[0];
  const float* Wc   = (const float*)d_in[1];
  const float* bn1g = (const float*)d_in[2];
  const float* bn1b = (const float*)d_in[3];
  const float* cqw  = (const float*)d_in[4];
  const float* cqb  = (const float*)d_in[5];
  const float* ckw  = (const float*)d_in[6];
  const float* ckb  = (const float*)d_in[7];
  const float* cvw  = (const float*)d_in[8];
  const float* cvb  = (const float*)d_in[9];
  const float* pqw  = (const float*)d_in[10];
  const float* pqb  = (const float*)d_in[11];
  const float* pkw  = (const float*)d_in[12];
  const float* pkb  = (const float*)d_in[13];
  const float* pvw  = (const float*)d_in[14];
  const float* pvb  = (const float*)d_in[15];
  const float* g1   = (const float*)d_in[16];
  const float* g2   = (const float*)d_in[17];
  const float* bn2g = (const float*)d_in[18];
  const float* bn2b = (const float*)d_in[19];
  const float* Wd   = (const float*)d_in[20];
  const float* bn3g = (const float*)d_in[21];
  const float* bn3b = (const float*)d_in[22];
  float* out = (float*)d_out;

  float* wsp = (float*)d_ws;
  size_t off = 0;
  auto alloc = [&](size_t nel) { float* p = wsp + off; off += nel; return p; };
  float* feat1 = alloc((size_t)B * C * N);
  float* y1    = alloc((size_t)B * C * N);
  float* qT    = alloc((size_t)B * NQ * C);
  float* kT    = alloc((size_t)B * NQ * C);
  unsigned short* vh   = (unsigned short*)alloc((size_t)B * N * C / 2);
  unsigned short* attn_h = (unsigned short*)alloc((size_t)B * C * C / 2 + 32);
  unsigned short* pvs  = (unsigned short*)alloc((size_t)B * C * N / 2);
  unsigned short* pq_t = (unsigned short*)alloc((size_t)B * N * 4);
  unsigned short* pks  = (unsigned short*)alloc((size_t)B * N * 4);
  unsigned* scpf = (unsigned*)alloc((size_t)SAP * B * NTP * 32 * 64);
  float* Lp    = alloc((size_t)SAP * B * N);
  unsigned short* fsumh = (unsigned short*)alloc((size_t)B * N * C / 2);  // bf16 NHWC
  float* y3    = alloc((size_t)B * C * N);
  float* part  = alloc((size_t)128 * B * NT3);
  float* part2 = alloc((size_t)128 * B * NTC);
  unsigned short* xt     = (unsigned short*)alloc((size_t)B * N * C / 2);
  unsigned short* feat1h = (unsigned short*)alloc((size_t)B * N * C / 2);
  unsigned short* x2t    = (unsigned short*)alloc((size_t)B * N * C / 2);
  unsigned short* w9c = (unsigned short*)alloc((size_t)9 * C * C / 2);
  unsigned short* w9d = (unsigned short*)alloc((size_t)9 * C * C / 2);
  unsigned short* w4q = (unsigned short*)alloc((size_t)4 * C * C / 2);
  unsigned short* w4k = (unsigned short*)alloc((size_t)4 * C * C / 2);
  float* stats = alloc(384);  // 3 BNs x (sum[64]+sumsq[64])
  float* s1 = stats;          // [0..63]=sum, [64..127]=sq
  float* s2 = stats + 128;
  float* s3 = stats + 256;

  // 1. weight transforms + x->NHWC (merged)
  xform_k<<<dim3(144, 5), 256, 0, stream>>>(x, Wc, Wd, cqw, ckw, xt, w9c, w9d, w4q, w4k);
  // 2. conv_c (+stats partials) -> reduce -> bn1
  conv3x3_mfma_k<<<dim3(NT3, B), 256, 0, stream>>>(xt, w9c, y1, part);
  bn_reduce_k<<<dim3(128), 256, 0, stream>>>(part, s1, B * NT3);
  bn1_apply_k<<<dim3(B * N / 256), 256, 0, stream>>>(y1, s1, s1 + 64, bn1g, bn1b,
                                                     feat1, feat1h);
  // CAM q/k conv + 1x1 projections
  conv2x2_mfma_k<<<dim3(NQ / 16, B), 64, 0, stream>>>(feat1h, w4q, cqb, w4k, ckb, qT, kT);
  proj_k<<<dim3(N / 256, 18, B), 256, 0, stream>>>(feat1, cvw, cvb, pvw, pvb, pqw, pqb,
                                                   pkw, pkb, vh, pvs, pq_t, pks);
  // CAM attention
  cam_attn_k<<<dim3(C, B), 512, 0, stream>>>(qT, kT, attn_h);
  // PAM flash attention (64 n/wave)
  pam_flash_k<<<dim3(NTP, SAP, B), 64, 0, stream>>>(pq_t, pks, pvs, scpf, Lp);
  // combine -> fsumh bf16 NHWC + stats partials -> reduce -> bn2
  combine_k<<<dim3(NTC, B), 64, 0, stream>>>(attn_h, vh, feat1h, scpf, Lp, g1, g2,
                                             fsumh, part2);
  bn_reduce_k<<<dim3(128), 256, 0, stream>>>(part2, s2, B * NTC);
  bn2_nhwc_k<<<dim3(B * N / 256), 256, 0, stream>>>(fsumh, s2, s2 + 64, bn2g, bn2b, x2t);
  // conv_d (+stats partials) -> reduce -> bn3
  conv3x3_mfma_k<<<dim3(NT3, B), 256, 0, stream>>>(x2t, w9d, y3, part);
  bn_reduce_k<<<dim3(128), 256, 0, stream>>>(part, s3, B * NT3);
  bn3_apply_k<<<dim3(B * C * N / 256), 256, 0, stream>>>(y3, s3, s3 + 64, bn3g, bn3b, out);
}